// Round 3
// baseline (11377.782 us; speedup 1.0000x reference)
//
#include <hip/hip_runtime.h>
#include <hip/hip_cooperative_groups.h>
#include <math.h>

namespace cg = cooperative_groups;

// Problem constants (fixed by setup_inputs)
#define T_DIM 1000
#define BB    16
#define XD    8
#define YD    4
#define HD    48
#define ED    104     // 2*HD + XD
#define TT    64      // time-tile per block
#define NTILE 16      // tiles per batch
#define NITER 200     // iterations (device scalar in d_in[26], fixed at 200)
#define GAMMA 1e-4f
#define HP    56      // padded h-width for [t][h] bf16 LDS tiles

typedef __attribute__((ext_vector_type(8))) short bf16x8;
typedef __attribute__((ext_vector_type(4))) float f32x4;
typedef __attribute__((ext_vector_type(4))) unsigned short us4;

#define MFMA16(a,b,c) __builtin_amdgcn_mfma_f32_16x16x32_bf16((a),(b),(c),0,0,0)

__device__ inline unsigned short f2b(float x) {
  union { float f; unsigned u; } v; v.f = x;
  unsigned r = (v.u + 0x7FFFu + ((v.u >> 16) & 1u)) >> 16;
  return (unsigned short)r;
}

__device__ inline bf16x8 ldg8(const unsigned short* p) { return *(const bf16x8*)p; }

// ---------------- precompute: inverses (lane-parallel, registers only) + fused mats ----------------
// mats layout: Qi[0..63], QiF[64..127], FtQi[128..191], FtQiF[192..255], HtRi[256..287], HtRiH[288..351]
__global__ __launch_bounds__(64) void precompute_mats_kernel(
    const float* __restrict__ F, const float* __restrict__ Hm,
    const float* __restrict__ Q, const float* __restrict__ R,
    float* __restrict__ mats)
{
  __shared__ float sQi[64], sRi[16], sF[64], sH[32], sFtQi[64], sHtRi[32];
  const int t = threadIdx.x;
  if (t < 64) sF[t] = F[t];
  if (t < 32) sH[t] = Hm[t];

  {
    float col[8];
    #pragma unroll
    for (int i = 0; i < 8; i++)
      col[i] = (t < 8) ? Q[i*8 + t] : ((t < 16 && i == t - 8) ? 1.f : 0.f);
    #pragma unroll
    for (int c = 0; c < 8; c++) {
      float Mcc = __shfl(col[c], c);
      float f[8];
      #pragma unroll
      for (int r = 0; r < 8; r++) f[r] = __shfl(col[r], c);
      float newc = col[c] / Mcc;
      col[c] = newc;
      #pragma unroll
      for (int r = 0; r < 8; r++) if (r != c) col[r] -= f[r] * newc;
    }
    if (t >= 8 && t < 16) {
      #pragma unroll
      for (int i = 0; i < 8; i++) sQi[i*8 + (t - 8)] = col[i];
    }
  }
  {
    float col[4];
    #pragma unroll
    for (int i = 0; i < 4; i++)
      col[i] = (t < 4) ? R[i*4 + t] : ((t < 8 && i == t - 4) ? 1.f : 0.f);
    #pragma unroll
    for (int c = 0; c < 4; c++) {
      float Mcc = __shfl(col[c], c);
      float f[4];
      #pragma unroll
      for (int r = 0; r < 4; r++) f[r] = __shfl(col[r], c);
      float newc = col[c] / Mcc;
      col[c] = newc;
      #pragma unroll
      for (int r = 0; r < 4; r++) if (r != c) col[r] -= f[r] * newc;
    }
    if (t >= 4 && t < 8) {
      #pragma unroll
      for (int i = 0; i < 4; i++) sRi[i*4 + (t - 4)] = col[i];
    }
  }
  __syncthreads();
  const int i = t >> 3, j = t & 7;
  mats[t] = sQi[t];
  { float s = 0.f; for (int k = 0; k < 8; k++) s += sQi[i*8+k] * sF[k*8+j]; mats[64 + t] = s; }
  { float s = 0.f; for (int k = 0; k < 8; k++) s += sF[k*8+i] * sQi[k*8+j]; mats[128 + t] = s; sFtQi[t] = s; }
  if (t < 32) {
    int ii = t >> 2, z = t & 3;
    float s = 0.f; for (int y = 0; y < 4; y++) s += sH[y*8+ii] * sRi[y*4+z];
    mats[256 + t] = s; sHtRi[t] = s;
  }
  __syncthreads();
  { float s = 0.f; for (int k = 0; k < 8; k++) s += sFtQi[i*8+k] * sF[k*8+j]; mats[192 + t] = s; }
  { float s = 0.f; for (int z = 0; z < 4; z++) s += sHtRi[i*4+z] * sH[z*8+j]; mats[288 + t] = s; }
}

// ---------------- precompute per (b,t): hy (bf16), xs0, mconst ----------------
__global__ void precompute_bt_kernel(const float* __restrict__ ys,
                                     const float* __restrict__ W_hy, const float* __restrict__ b_hy,
                                     const float* __restrict__ Hm, const float* __restrict__ mats,
                                     unsigned short* __restrict__ hy_b,
                                     float* __restrict__ mconst, float* __restrict__ xs0)
{
  int idx = blockIdx.x * 256 + threadIdx.x;
  if (idx >= BB * T_DIM) return;
  int b = idx / T_DIM, t = idx - b * T_DIM;
  float yy[YD];
  #pragma unroll
  for (int y = 0; y < YD; y++) yy[y] = ys[(b*T_DIM + t)*YD + y];
  #pragma unroll 4
  for (int h = 0; h < HD; h++) {
    float s = b_hy[h];
    #pragma unroll
    for (int y = 0; y < YD; y++) s += W_hy[h*YD+y] * yy[y];
    hy_b[(b*T_DIM + t)*HD + h] = f2b(s);
  }
  const float* HtRi = mats + 256;
  #pragma unroll
  for (int x = 0; x < XD; x++) {
    float s0 = 0.f, s1 = 0.f;
    #pragma unroll
    for (int y = 0; y < YD; y++) {
      s0 += Hm[y*XD + x] * yy[y];
      s1 += HtRi[x*YD + y] * yy[y];
    }
    xs0[(b*XD + x)*T_DIM + t]    = s0;
    mconst[(b*XD + x)*T_DIM + t] = s1;
  }
}

// ---------------- weight conversion to padded bf16 ----------------
struct WP {
  const float *W1[3], *W2[3], *b2[3], *Wih, *Whh, *Wdec;
  unsigned short *W1b, *W2b, *Wihb, *Whhb, *Wdecb;
  float* b2sum;
};
__global__ void convert_weights_kernel(WP p) {
  int idx = blockIdx.x * 256 + threadIdx.x;
  int stride = gridDim.x * 256;
  for (int i = idx; i < 3*48*128; i += stride) {
    int e = i / (48*128), r = (i / 128) % 48, k = i & 127;
    p.W1b[i] = (k < ED) ? f2b(p.W1[e][r*ED + k]) : 0;
  }
  for (int i = idx; i < 3*48*64; i += stride) {
    int e = i / (48*64), r = (i / 64) % 48, k = i & 63;
    p.W2b[i] = (k < HD) ? f2b(p.W2[e][r*HD + k]) : 0;
  }
  for (int i = idx; i < 144*64; i += stride) {
    int r = i >> 6, k = i & 63;
    p.Wihb[i] = (k < HD) ? f2b(p.Wih[r*HD + k]) : 0;
    p.Whhb[i] = (k < HD) ? f2b(p.Whh[r*HD + k]) : 0;
  }
  for (int i = idx; i < 16*64; i += stride) {
    int r = i >> 6, k = i & 63;
    p.Wdecb[i] = (r < XD && k < HD) ? f2b(p.Wdec[r*HD + k]) : 0;
  }
  for (int i = idx; i < HD; i += stride)
    p.b2sum[i] = p.b2[0][i] + p.b2[1][i] + p.b2[2][i];
}

// ---------------- persistent cooperative scan kernel ----------------
struct PP {
  const float* mats;
  const float* mconst;
  const unsigned short* hy_b;
  const unsigned short *W1b, *W2b, *Wihb, *Whhb, *Wdecb;
  const float* b2sum;
  const float *b1_0, *b1_1, *b1_2, *bih, *bhh, *bdec;
  const float *xs0, *hx0;
  float* out;      // [BXT final xs][NITER][B][XD][T]
  float* hxEdge;   // [B][NTILE][2][HD] fp32
};

__global__ __launch_bounds__(512)
void persist_kernel(PP P)
{
  cg::grid_group gg = cg::this_grid();

  __shared__ float s_mats[352];
  __shared__ float s_xs[XD][TT+2];
  __shared__ float s_mf[3][XD][TT];
  __shared__ float s_hx32[TT][HD];                          // fp32 hx (exact GRU carry)
  __shared__ __align__(16) unsigned short s_hxb[TT+2][HP];  // bf16 hx + halo
  __shared__ __align__(16) unsigned short s_hyb[TT][HP];    // bf16 hy (constant)
  __shared__ __align__(16) unsigned short s_mb[3][TT][8];   // bf16 messages
  __shared__ __align__(16) unsigned short s_buf[TT][HP];    // mid / agg scratch

  const int tid  = threadIdx.x;
  const int bid  = blockIdx.x;
  const int b    = bid >> 4;
  const int tile = bid & 15;
  const int t0   = tile * TT;
  const int wave = tid >> 6;
  const int lane = tid & 63;
  const int quad = lane >> 4;
  const int l16  = lane & 15;

  const size_t BXT = (size_t)BB * XD * T_DIM;
  const float* b1e_arr[3] = { P.b1_0, P.b1_1, P.b1_2 };

  // ---- one-time staging ----
  for (int i = tid; i < 352; i += 512) s_mats[i] = P.mats[i];
  for (int i = tid; i < XD*(TT+2); i += 512) {
    int r = i / (TT+2), c = i - r*(TT+2);
    int g = t0 + c - 1;
    s_xs[r][c] = (g >= 0 && g < T_DIM) ? P.xs0[(b*XD + r)*T_DIM + g] : 0.f;
  }
  for (int i = tid; i < HD*(TT+2); i += 512) {
    int h = i / (TT+2), c = i - h*(TT+2);
    int g = t0 + c - 1;
    float v = (g >= 0 && g < T_DIM) ? P.hx0[(b*HD + h)*T_DIM + g] : 0.f;
    s_hxb[c][h] = f2b(v);
    if (c >= 1 && c <= TT) s_hx32[c-1][h] = v;
  }
  for (int i = tid; i < (TT+2)*8; i += 512) s_hxb[i >> 3][HD + (i & 7)] = 0;
  for (int i = tid; i < TT*HD; i += 512) {
    int t = i / HD, h = i - t*HD;
    int g = t0 + t;
    s_hyb[t][h] = (g < T_DIM) ? P.hy_b[(b*T_DIM + g)*HD + h] : 0;
  }

  const bf16x8 zf = {0,0,0,0,0,0,0,0};
  const int njob = (wave < 4) ? 2 : 1;
  int jobs[2]; jobs[0] = wave; jobs[1] = wave + 8;

  #pragma unroll 1
  for (int k = 0; k < NITER; k++) {
    float* out_k = P.out + BXT + (size_t)k * BXT;
    __syncthreads();   // staging / halo refresh visible

    // ---- messages (fp32): 512 threads = 8 x-rows * 64 t ----
    {
      const int x = tid >> 6, t = tid & 63;
      const int gt = t0 + t, tc = t + 1;
      const float* Qi    = s_mats;
      const float* QiF   = s_mats + 64;
      const float* FtQi  = s_mats + 128;
      const float* FtQiF = s_mats + 192;
      const float* HtRiH = s_mats + 288;
      float mp = 0.f, mf = 0.f, my = 0.f;
      #pragma unroll
      for (int j = 0; j < 8; j++) {
        float xc  = s_xs[j][tc];
        float xpv = s_xs[j][tc-1];
        float xfv = s_xs[j][tc+1];
        mp += QiF[x*8+j]  * xpv - Qi[x*8+j]    * xc;
        mf += FtQi[x*8+j] * xfv - FtQiF[x*8+j] * xc;
        my -= HtRiH[x*8+j] * xc;
      }
      if (gt < T_DIM) my += P.mconst[(b*XD + x)*T_DIM + gt]; else my = 0.f;
      if (gt == 0) mp = 0.f;
      if (gt >= T_DIM - 1) mf = 0.f;
      s_mf[0][x][t] = mp; s_mf[1][x][t] = mf; s_mf[2][x][t] = my;
      s_mb[0][t][x] = f2b(mp); s_mb[1][t][x] = f2b(mf); s_mb[2][t][x] = f2b(my);
    }
    __syncthreads();

    // agg accumulators, init with b2sum
    f32x4 agg[2];
    for (int s = 0; s < njob; s++) {
      int rt = jobs[s] >> 2;
      #pragma unroll
      for (int r = 0; r < 4; r++) agg[s][r] = P.b2sum[rt*16 + quad*4 + r];
    }

    // ---- three edges ----
    #pragma unroll 1
    for (int e = 0; e < 3; e++) {
      const unsigned short* W1e = P.W1b + e*48*128;
      const unsigned short* W2e = P.W2b + e*48*64;
      const float* b1e = b1e_arr[e];

      f32x4 mid[2];
      for (int s = 0; s < njob; s++) {
        int j = jobs[s], rt = j >> 2, ct = j & 3, lt = ct*16 + l16;
        f32x4 acc = {0.f,0.f,0.f,0.f};
        #pragma unroll
        for (int k0 = 0; k0 < 128; k0 += 32) {
          int ks = k0 + quad*8;
          bf16x8 a = ldg8(W1e + (rt*16 + l16)*128 + ks);
          bf16x8 bf;
          if (ks < 48)       bf = ldg8(&s_hxb[lt+1][ks]);
          else if (ks < 96)  bf = (e == 0) ? ldg8(&s_hxb[lt][ks-48])
                                : (e == 1) ? ldg8(&s_hxb[lt+2][ks-48])
                                           : ldg8(&s_hyb[lt][ks-48]);
          else if (ks == 96) bf = ldg8(&s_mb[e][lt][0]);
          else               bf = zf;
          acc = MFMA16(a, bf, acc);
        }
        mid[s] = acc;
      }
      for (int s = 0; s < njob; s++) {
        int j = jobs[s], rt = j >> 2, ct = j & 3, lt = ct*16 + l16;
        us4 pk;
        #pragma unroll
        for (int r = 0; r < 4; r++) {
          int row = rt*16 + quad*4 + r;
          pk[r] = f2b(fmaxf(mid[s][r] + b1e[row], 0.f));
        }
        *(us4*)&s_buf[lt][rt*16 + quad*4] = pk;
      }
      __syncthreads();
      for (int s = 0; s < njob; s++) {
        int j = jobs[s], rt = j >> 2, ct = j & 3, lt = ct*16 + l16;
        f32x4 acc = agg[s];
        #pragma unroll
        for (int k0 = 0; k0 < 64; k0 += 32) {
          int ks = k0 + quad*8;
          bf16x8 a = ldg8(W2e + (rt*16 + l16)*64 + ks);
          bf16x8 bf = (ks < 48) ? ldg8(&s_buf[lt][ks]) : zf;
          acc = MFMA16(a, bf, acc);
        }
        agg[s] = acc;
      }
      __syncthreads();
    }

    // ---- agg -> s_buf (bf16) ----
    for (int s = 0; s < njob; s++) {
      int j = jobs[s], rt = j >> 2, ct = j & 3, lt = ct*16 + l16;
      us4 pk;
      #pragma unroll
      for (int r = 0; r < 4; r++) pk[r] = f2b(agg[s][r]);
      *(us4*)&s_buf[lt][rt*16 + quad*4] = pk;
    }
    __syncthreads();

    // ---- GRU MFMA: gx = Wih@agg, gh = Whh@hx ----
    f32x4 gru[2][6];
    for (int s = 0; s < njob; s++) {
      int j = jobs[s], rt = j >> 2, ct = j & 3, lt = ct*16 + l16;
      #pragma unroll
      for (int g3 = 0; g3 < 3; g3++) {
        f32x4 ax = {0.f,0.f,0.f,0.f}, ah = {0.f,0.f,0.f,0.f};
        #pragma unroll
        for (int k0 = 0; k0 < 64; k0 += 32) {
          int ks = k0 + quad*8;
          bf16x8 aA = ldg8(P.Wihb + (g3*48 + rt*16 + l16)*64 + ks);
          bf16x8 aH = ldg8(P.Whhb + (g3*48 + rt*16 + l16)*64 + ks);
          bf16x8 bA = (ks < 48) ? ldg8(&s_buf[lt][ks]) : zf;
          bf16x8 bH = (ks < 48) ? ldg8(&s_hxb[lt+1][ks]) : zf;
          ax = MFMA16(aA, bA, ax);
          ah = MFMA16(aH, bH, ah);
        }
        gru[s][g3] = ax; gru[s][3+g3] = ah;
      }
    }
    __syncthreads();   // old-hx and agg reads done

    // ---- GRU epilogue: gates fp32; hnew -> s_hx32, s_hxb, hxEdge ----
    for (int s = 0; s < njob; s++) {
      int j = jobs[s], rt = j >> 2, ct = j & 3, lt = ct*16 + l16;
      int gt = t0 + lt;
      #pragma unroll
      for (int r = 0; r < 4; r++) {
        int h = rt*16 + quad*4 + r;
        float ar = gru[s][0][r] + P.bih[h];
        float az = gru[s][1][r] + P.bih[48 + h];
        float an = gru[s][2][r] + P.bih[96 + h];
        float hr = gru[s][3][r] + P.bhh[h];
        float hz = gru[s][4][r] + P.bhh[48 + h];
        float hn = gru[s][5][r] + P.bhh[96 + h];
        float rg = 1.f / (1.f + __expf(-(ar + hr)));
        float zg = 1.f / (1.f + __expf(-(az + hz)));
        float na = an + rg * hn;
        float e2 = __expf(2.f * na);
        float n  = 1.f - 2.f / (e2 + 1.f);   // tanh
        float hcur = s_hx32[lt][h];
        float hnew = (1.f - zg) * n + zg * hcur;
        if (gt >= T_DIM) hnew = 0.f;         // keep invalid columns zero (pad semantics)
        s_hx32[lt][h] = hnew;
        s_hxb[lt+1][h] = f2b(hnew);
        if (lt == 0)      P.hxEdge[((b*NTILE + tile)*2 + 0)*HD + h] = hnew;
        else if (lt == TT-1) P.hxEdge[((b*NTILE + tile)*2 + 1)*HD + h] = hnew;
      }
    }
    __syncthreads();

    // ---- decoder + xs update (waves 0..3), in-place s_xs + out ----
    if (wave < 4) {
      int ct = wave, lt = ct*16 + l16, gt = t0 + lt;
      f32x4 acc = {0.f,0.f,0.f,0.f};
      #pragma unroll
      for (int k0 = 0; k0 < 64; k0 += 32) {
        int ks = k0 + quad*8;
        bf16x8 a = ldg8(P.Wdecb + l16*64 + ks);
        bf16x8 bf = (ks < 48) ? ldg8(&s_hxb[lt+1][ks]) : zf;
        acc = MFMA16(a, bf, acc);
      }
      #pragma unroll
      for (int r = 0; r < 4; r++) {
        int x = quad*4 + r;
        if (x < XD) {
          float eps  = acc[r] + P.bdec[x];
          float msum = s_mf[0][x][lt] + s_mf[1][x][lt] + s_mf[2][x][lt];
          float xnew = s_xs[x][lt+1] + GAMMA * (eps + msum);
          if (gt >= T_DIM) xnew = 0.f;
          s_xs[x][lt+1] = xnew;
          if (gt < T_DIM) {
            out_k[(b*XD + x)*T_DIM + gt] = xnew;
            if (k == NITER-1) P.out[(b*XD + x)*T_DIM + gt] = xnew;
          }
        }
      }
    }

    gg.sync();

    // ---- halo refresh for next iteration ----
    if (k + 1 < NITER) {
      if (tid < 16) {
        int x = tid >> 1, side = tid & 1;
        int g = side ? (t0 + TT) : (t0 - 1);
        s_xs[x][side ? TT+1 : 0] =
            (g >= 0 && g < T_DIM) ? out_k[(b*XD + x)*T_DIM + g] : 0.f;
      } else if (tid >= 64 && tid < 160) {
        int i = tid - 64, side = i / 48, h = i - side*48;
        int ntile = side ? tile + 1 : tile - 1;
        float v = 0.f;
        if (ntile >= 0 && ntile < NTILE)
          v = P.hxEdge[((b*NTILE + ntile)*2 + (side ? 0 : 1))*HD + h];
        s_hxb[side ? TT+1 : 0][h] = f2b(v);
      }
    }
  }
}

// ---------------- host launch ----------------
extern "C" void kernel_launch(void* const* d_in, const int* in_sizes, int n_in,
                              void* d_out, int out_size, void* d_ws, size_t ws_size,
                              hipStream_t stream) {
  (void)in_sizes; (void)n_in; (void)out_size; (void)ws_size;
  const float* ys  = (const float*)d_in[0];
  const float* hx0 = (const float*)d_in[1];
  const float* F   = (const float*)d_in[2];
  const float* Hm  = (const float*)d_in[3];
  const float* Q   = (const float*)d_in[4];
  const float* R   = (const float*)d_in[5];

  float* out = (float*)d_out;
  float* ws  = (float*)d_ws;

  const size_t BXT = (size_t)BB * XD * T_DIM;   // 128000
  const size_t BHT = (size_t)BB * HD * T_DIM;   // 768000

  float* mats   = ws;                      // 512
  float* mconst = ws + 512;                // 128000
  float* xs0    = mconst + BXT;            // 128000
  float* hxEdge = xs0 + BXT;               // 16*16*2*48 = 24576
  unsigned short* hy_b  = (unsigned short*)(hxEdge + 24576);  // 768000
  unsigned short* W1b   = hy_b + BHT;
  unsigned short* W2b   = W1b + 3*48*128;
  unsigned short* Wihb  = W2b + 3*48*64;
  unsigned short* Whhb  = Wihb + 144*64;
  unsigned short* Wdecb = Whhb + 144*64;
  float* b2sum = (float*)(Wdecb + 16*64);

  precompute_mats_kernel<<<1, 64, 0, stream>>>(F, Hm, Q, R, mats);
  precompute_bt_kernel<<<(BB*T_DIM + 255)/256, 256, 0, stream>>>(
      ys, (const float*)d_in[6], (const float*)d_in[7], Hm, mats, hy_b, mconst, xs0);

  WP wp;
  wp.W1[0] = (const float*)d_in[8];  wp.W2[0] = (const float*)d_in[10]; wp.b2[0] = (const float*)d_in[11];
  wp.W1[1] = (const float*)d_in[12]; wp.W2[1] = (const float*)d_in[14]; wp.b2[1] = (const float*)d_in[15];
  wp.W1[2] = (const float*)d_in[16]; wp.W2[2] = (const float*)d_in[18]; wp.b2[2] = (const float*)d_in[19];
  wp.Wih = (const float*)d_in[20]; wp.Whh = (const float*)d_in[22]; wp.Wdec = (const float*)d_in[24];
  wp.W1b = W1b; wp.W2b = W2b; wp.Wihb = Wihb; wp.Whhb = Whhb; wp.Wdecb = Wdecb; wp.b2sum = b2sum;
  convert_weights_kernel<<<32, 256, 0, stream>>>(wp);

  PP P;
  P.mats = mats; P.mconst = mconst; P.hy_b = hy_b;
  P.W1b = W1b; P.W2b = W2b; P.Wihb = Wihb; P.Whhb = Whhb; P.Wdecb = Wdecb;
  P.b2sum = b2sum;
  P.b1_0 = (const float*)d_in[9];
  P.b1_1 = (const float*)d_in[13];
  P.b1_2 = (const float*)d_in[17];
  P.bih  = (const float*)d_in[21];
  P.bhh  = (const float*)d_in[23];
  P.bdec = (const float*)d_in[25];
  P.xs0 = xs0; P.hx0 = hx0;
  P.out = out; P.hxEdge = hxEdge;

  void* args[] = { &P };
  hipLaunchCooperativeKernel((void*)persist_kernel, dim3(BB * NTILE), dim3(512),
                             args, 0, stream);
}

// Round 5
// 4814.458 us; speedup vs baseline: 2.3633x; 2.3633x over previous
//
#include <hip/hip_runtime.h>
#include <math.h>

// Problem constants (fixed by setup_inputs)
#define T_DIM 1000
#define BB    16
#define XD    8
#define YD    4
#define HD    48
#define NITER 200     // iterations (device scalar d_in[26], fixed)
#define GAMMA 1e-4f

// fused-scan geometry
#define HALO  25      // ghost columns each side
#define FUSE  25      // iterations fused per launch (valid shrink = HALO)
#define NLNCH 8       // FUSE*NLNCH == NITER
#define SC    128     // staged columns per block (8 waves x 16)
#define EFF   (SC - 2*HALO)   // 78 effective columns
#define NTI   13      // ceil(1000/EFF)
#define HP    56      // padded h-width (shorts) for [col][h] LDS tiles

typedef __attribute__((ext_vector_type(8))) short bf16x8;
typedef __attribute__((ext_vector_type(4))) float f32x4;
typedef __attribute__((ext_vector_type(4))) unsigned short us4;

#define MFMA16(a,b,c) __builtin_amdgcn_mfma_f32_16x16x32_bf16((a),(b),(c),0,0,0)

__device__ inline unsigned short f2b(float x) {
  union { float f; unsigned u; } v; v.f = x;
  unsigned r = (v.u + 0x7FFFu + ((v.u >> 16) & 1u)) >> 16;
  return (unsigned short)r;
}
__device__ inline bf16x8 ldg8(const unsigned short* p) { return *(const bf16x8*)p; }

// ---------------- precompute: inverses (lane-parallel) + fused mats ----------------
// mats: Qi[0..63], QiF[64..127], FtQi[128..191], FtQiF[192..255], HtRi[256..287], HtRiH[288..351]
__global__ __launch_bounds__(64) void precompute_mats_kernel(
    const float* __restrict__ F, const float* __restrict__ Hm,
    const float* __restrict__ Q, const float* __restrict__ R,
    float* __restrict__ mats)
{
  __shared__ float sQi[64], sRi[16], sF[64], sH[32], sFtQi[64], sHtRi[32];
  const int t = threadIdx.x;
  if (t < 64) sF[t] = F[t];
  if (t < 32) sH[t] = Hm[t];
  {
    float col[8];
    #pragma unroll
    for (int i = 0; i < 8; i++)
      col[i] = (t < 8) ? Q[i*8 + t] : ((t < 16 && i == t - 8) ? 1.f : 0.f);
    #pragma unroll
    for (int c = 0; c < 8; c++) {
      float Mcc = __shfl(col[c], c);
      float f[8];
      #pragma unroll
      for (int r = 0; r < 8; r++) f[r] = __shfl(col[r], c);
      float newc = col[c] / Mcc;
      col[c] = newc;
      #pragma unroll
      for (int r = 0; r < 8; r++) if (r != c) col[r] -= f[r] * newc;
    }
    if (t >= 8 && t < 16) {
      #pragma unroll
      for (int i = 0; i < 8; i++) sQi[i*8 + (t - 8)] = col[i];
    }
  }
  {
    float col[4];
    #pragma unroll
    for (int i = 0; i < 4; i++)
      col[i] = (t < 4) ? R[i*4 + t] : ((t < 8 && i == t - 4) ? 1.f : 0.f);
    #pragma unroll
    for (int c = 0; c < 4; c++) {
      float Mcc = __shfl(col[c], c);
      float f[4];
      #pragma unroll
      for (int r = 0; r < 4; r++) f[r] = __shfl(col[r], c);
      float newc = col[c] / Mcc;
      col[c] = newc;
      #pragma unroll
      for (int r = 0; r < 4; r++) if (r != c) col[r] -= f[r] * newc;
    }
    if (t >= 4 && t < 8) {
      #pragma unroll
      for (int i = 0; i < 4; i++) sRi[i*4 + (t - 4)] = col[i];
    }
  }
  __syncthreads();
  const int i = t >> 3, j = t & 7;
  mats[t] = sQi[t];
  { float s = 0.f; for (int k = 0; k < 8; k++) s += sQi[i*8+k] * sF[k*8+j]; mats[64 + t] = s; }
  { float s = 0.f; for (int k = 0; k < 8; k++) s += sF[k*8+i] * sQi[k*8+j]; mats[128 + t] = s; sFtQi[t] = s; }
  if (t < 32) {
    int ii = t >> 2, z = t & 3;
    float s = 0.f; for (int y = 0; y < 4; y++) s += sH[y*8+ii] * sRi[y*4+z];
    mats[256 + t] = s; sHtRi[t] = s;
  }
  __syncthreads();
  { float s = 0.f; for (int k = 0; k < 8; k++) s += sFtQi[i*8+k] * sF[k*8+j]; mats[192 + t] = s; }
  { float s = 0.f; for (int z = 0; z < 4; z++) s += sHtRi[i*4+z] * sH[z*8+j]; mats[288 + t] = s; }
}

// ---------------- precompute per (b,t): hy (bf16), xs0, mconst ----------------
__global__ void precompute_bt_kernel(const float* __restrict__ ys,
                                     const float* __restrict__ W_hy, const float* __restrict__ b_hy,
                                     const float* __restrict__ Hm, const float* __restrict__ mats,
                                     unsigned short* __restrict__ hy_b,
                                     float* __restrict__ mconst, float* __restrict__ xs0)
{
  int idx = blockIdx.x * 256 + threadIdx.x;
  if (idx >= BB * T_DIM) return;
  int b = idx / T_DIM, t = idx - b * T_DIM;
  float yy[YD];
  #pragma unroll
  for (int y = 0; y < YD; y++) yy[y] = ys[(b*T_DIM + t)*YD + y];
  #pragma unroll 4
  for (int h = 0; h < HD; h++) {
    float s = b_hy[h];
    #pragma unroll
    for (int y = 0; y < YD; y++) s += W_hy[h*YD+y] * yy[y];
    hy_b[(b*T_DIM + t)*HD + h] = f2b(s);
  }
  const float* HtRi = mats + 256;
  #pragma unroll
  for (int x = 0; x < XD; x++) {
    float s0 = 0.f, s1 = 0.f;
    #pragma unroll
    for (int y = 0; y < YD; y++) {
      s0 += Hm[y*XD + x] * yy[y];
      s1 += HtRi[x*YD + y] * yy[y];
    }
    xs0[(b*XD + x)*T_DIM + t]    = s0;
    mconst[(b*XD + x)*T_DIM + t] = s1;
  }
}

// ---------------- weight conversion to padded bf16 with bias folded into K ----------------
struct WP {
  const float *W1[3], *b1[3], *W2[3], *b2[3], *Wih, *bih, *Whh, *bhh, *Wdec, *bdec;
  unsigned short *W1b, *W2b, *Wihb, *Whhb, *Wdecb;
};
__global__ void convert_weights_kernel(WP p) {
  int idx = blockIdx.x * 256 + threadIdx.x;
  int stride = gridDim.x * 256;
  // W1b: [3][48][128] : cols 0..103 = W1, col 104 = b1, rest 0
  for (int i = idx; i < 3*48*128; i += stride) {
    int e = i / (48*128), r = (i / 128) % 48, k = i & 127;
    float v = (k < 104) ? p.W1[e][r*104 + k] : (k == 104) ? p.b1[e][r] : 0.f;
    p.W1b[i] = (k <= 104) ? f2b(v) : 0;
  }
  // W2b: [3][48][64] : cols 0..47 = W2, col 48 = b2
  for (int i = idx; i < 3*48*64; i += stride) {
    int e = i / (48*64), r = (i / 64) % 48, k = i & 63;
    float v = (k < HD) ? p.W2[e][r*HD + k] : (k == HD) ? p.b2[e][r] : 0.f;
    p.W2b[i] = (k <= HD) ? f2b(v) : 0;
  }
  // Wihb/Whhb: [144][64] : col 48 = bias
  for (int i = idx; i < 144*64; i += stride) {
    int r = i >> 6, k = i & 63;
    p.Wihb[i] = (k < HD) ? f2b(p.Wih[r*HD + k]) : (k == HD) ? f2b(p.bih[r]) : 0;
    p.Whhb[i] = (k < HD) ? f2b(p.Whh[r*HD + k]) : (k == HD) ? f2b(p.bhh[r]) : 0;
  }
  // Wdecb: [16][64]
  for (int i = idx; i < 16*64; i += stride) {
    int r = i >> 6, k = i & 63;
    unsigned short v = 0;
    if (r < XD) {
      if (k < HD) v = f2b(p.Wdec[r*HD + k]);
      else if (k == HD) v = f2b(p.bdec[r]);
    }
    p.Wdecb[i] = v;
  }
}

// ---------------- fused multi-iteration scan kernel ----------------
struct FP {
  const float* mats;
  const float* mconst;
  const unsigned short* hy_b;
  const unsigned short *W1b, *W2b, *Wihb, *Whhb, *Wdecb;
  const float *xs_src, *hx_src;   // state after iteration k0-1
  float* hx_dst;                  // state after iteration k0+FUSE-1
  float* out;                     // [BXT final][NITER][B][XD][T]
  int k0;
};

__global__ __launch_bounds__(512, 2)
void fused_kernel(FP P)
{
  // declaration order chosen so small 16B read-overruns (ks=56 trick) land in
  // adjacent LDS arrays whose product-weights are zero. ALL such aliased
  // regions must be initialized (0 x NaN = NaN in MFMA!) -> full zero-init
  // of s_mid h<48 and s_hx[1] interior h<48 at staging.
  __shared__ __align__(16) unsigned short s_hx[2][SC+2][HP];  // bf16 hx, dbuf, rows=col+1, col 48=1.0(bias)
  __shared__ __align__(16) unsigned short s_mid[SC][HP];      // mid/agg scratch, col 48=1.0
  __shared__ __align__(16) unsigned short s_hy[SC][HP];       // bf16 hy (const)
  __shared__ __align__(16) unsigned short s_mb[3][SC][8];     // bf16 messages per edge
  __shared__ __align__(16) float s_xs[2][SC+2][12];           // fp32 xs, dbuf
  __shared__ __align__(16) float s_mconst[SC][8];
  __shared__ __align__(16) float s_msum[SC][8];
  __shared__ float s_mats[352];
  __shared__ __align__(16) unsigned short s_pad[16];          // [0..7]={1,0..}, [8..15]=0

  const int tid  = threadIdx.x;
  const int b    = blockIdx.x / NTI;
  const int tile = blockIdx.x % NTI;
  const int goff = tile * EFF - HALO;
  const int wave = tid >> 6;
  const int lane = tid & 63;
  const int quad = lane >> 4;
  const int l16  = lane & 15;
  const int col  = wave * 16 + l16;        // this lane's column (0..127)
  const int gt   = goff + col;             // global time of this column
  const size_t BXT = (size_t)BB * XD * T_DIM;

  // ---- one-time staging ----
  for (int i = tid; i < 352; i += 512) s_mats[i] = P.mats[i];
  if (tid < 16) s_pad[tid] = (tid == 0) ? (unsigned short)0x3F80 : 0;
  for (int i = tid; i < SC*8; i += 512) {
    int c = i >> 3, x = i & 7, g = goff + c;
    s_mconst[c][x] = (g >= 0 && g < T_DIM) ? P.mconst[((size_t)b*XD + x)*T_DIM + g] : 0.f;
  }
  for (int i = tid; i < SC*HP; i += 512) {
    int c = i / HP, h = i - c*HP, g = goff + c;
    s_hy[c][h] = (h < HD && g >= 0 && g < T_DIM) ? P.hy_b[((size_t)b*T_DIM + g)*HD + h] : 0;
  }
  // s_mid: zero h<48 (overrun-aliased region), bias col at h=48, zeros beyond
  for (int i = tid; i < SC*HP; i += 512) {
    int c = i / HP, h = i - c*HP;
    s_mid[c][h] = (h == HD) ? (unsigned short)0x3F80 : 0;
  }
  for (int i = tid; i < (SC+2)*HP; i += 512) {
    int c = i / HP, h = i - c*HP;
    if (c == 0 || c == SC+1) { s_hx[0][c][h] = 0; s_hx[1][c][h] = 0; }
    else if (h < HD) {
      int g = goff + c - 1;
      float v = (g >= 0 && g < T_DIM) ? P.hx_src[((size_t)b*HD + h)*T_DIM + g] : 0.f;
      s_hx[0][c][h] = f2b(v);
      s_hx[1][c][h] = 0;                    // finite init: overrun reads at j=0
    } else {
      unsigned short v = (h == HD) ? (unsigned short)0x3F80 : 0;
      s_hx[0][c][h] = v; s_hx[1][c][h] = v;
    }
  }
  for (int i = tid; i < (SC+2)*12; i += 512) {
    int c = i / 12, x = i - c*12;
    float v = 0.f;
    if (c >= 1 && c <= SC && x < XD) {
      int g = goff + c - 1;
      if (g >= 0 && g < T_DIM) v = P.xs_src[((size_t)b*XD + x)*T_DIM + g];
    }
    s_xs[0][c][x] = v;
    if (c == 0 || c == SC+1) s_xs[1][c][x] = 0.f;
  }
  // per-lane fp32 hx carry (exact GRU z*h path)
  float hcur[3][4];
  #pragma unroll
  for (int rt = 0; rt < 3; rt++)
    #pragma unroll
    for (int r = 0; r < 4; r++) {
      int h = rt*16 + quad*4 + r;
      hcur[rt][r] = (gt >= 0 && gt < T_DIM) ? P.hx_src[((size_t)b*HD + h)*T_DIM + gt] : 0.f;
    }
  __syncthreads();

  const bool eff = (col >= HALO) && (col < HALO + EFF);
  const bool gtv = (gt >= 0) && (gt < T_DIM);

  #pragma unroll 1
  for (int j = 0; j < FUSE; j++) {
    const int p = j & 1;
    const unsigned short (*hxP)[HP] = s_hx[p];
    unsigned short (*hxN)[HP] = s_hx[p ^ 1];
    const float (*xsP)[12] = s_xs[p];
    float (*xsN)[12] = s_xs[p ^ 1];
    const int k = P.k0 + j;
    float* out_k = P.out + BXT + (size_t)k * BXT;

    // ---- messages (fp32, wave-local output) ----
    float xc[8], xp[8], xf[8];
    *(f32x4*)&xc[0] = *(const f32x4*)&xsP[col+1][0];
    *(f32x4*)&xc[4] = *(const f32x4*)&xsP[col+1][4];
    *(f32x4*)&xp[0] = *(const f32x4*)&xsP[col][0];
    *(f32x4*)&xp[4] = *(const f32x4*)&xsP[col][4];
    *(f32x4*)&xf[0] = *(const f32x4*)&xsP[col+2][0];
    *(f32x4*)&xf[4] = *(const f32x4*)&xsP[col+2][4];
    #pragma unroll
    for (int xx = 0; xx < 2; xx++) {
      const int x = quad*2 + xx;
      float mp = 0.f, mf = 0.f, my = s_mconst[col][x];
      #pragma unroll
      for (int jj = 0; jj < 8; jj++) {
        mp += s_mats[64  + x*8 + jj] * xp[jj] - s_mats[x*8 + jj]       * xc[jj];
        mf += s_mats[128 + x*8 + jj] * xf[jj] - s_mats[192 + x*8 + jj] * xc[jj];
        my -= s_mats[288 + x*8 + jj] * xc[jj];
      }
      if (gt == 0) mp = 0.f;
      if (gt == T_DIM - 1) mf = 0.f;
      s_msum[col][x] = mp + mf + my;
      s_mb[0][col][x] = f2b(mp);
      s_mb[1][col][x] = f2b(mf);
      s_mb[2][col][x] = f2b(my);
    }
    // no barrier: everything below consumes only this wave's own columns

    // ---- three edge MLPs (bias folded into K) ----
    f32x4 agg[3] = {{0,0,0,0},{0,0,0,0},{0,0,0,0}};
    #pragma unroll
    for (int e = 0; e < 3; e++) {
      const unsigned short* W1e = P.W1b + e*48*128;
      const unsigned short* W2e = P.W2b + e*48*64;
      const unsigned short* nb  = (e == 0) ? &hxP[col][0]
                                : (e == 1) ? &hxP[col+2][0]
                                           : &s_hy[col][0];
      const unsigned short* ctr = &hxP[col+1][0];
      bf16x8 b0 = ldg8(ctr + quad*8);
      bf16x8 b1 = ldg8((quad < 2) ? ctr + 32 + quad*8 : nb + (quad & 1)*8);
      bf16x8 b2 = ldg8(nb + 16 + quad*8);
      bf16x8 b3 = ldg8((quad == 0) ? &s_mb[e][col][0]
                      : (quad == 1) ? &s_pad[0] : &s_pad[8]);
      f32x4 mid[3];
      #pragma unroll
      for (int rt = 0; rt < 3; rt++) {
        const unsigned short* wr = W1e + (rt*16 + l16)*128;
        f32x4 acc = {0,0,0,0};
        acc = MFMA16(ldg8(wr + quad*8),      b0, acc);
        acc = MFMA16(ldg8(wr + 32 + quad*8), b1, acc);
        acc = MFMA16(ldg8(wr + 64 + quad*8), b2, acc);
        acc = MFMA16(ldg8(wr + 96 + quad*8), b3, acc);
        mid[rt] = acc;
      }
      #pragma unroll
      for (int rt = 0; rt < 3; rt++) {
        us4 pk;
        #pragma unroll
        for (int r = 0; r < 4; r++) pk[r] = f2b(fmaxf(mid[rt][r], 0.f));
        *(us4*)&s_mid[col][rt*16 + quad*4] = pk;
      }
      bf16x8 c0 = ldg8(&s_mid[col][quad*8]);        // same-wave DS in-order
      bf16x8 c1 = ldg8(&s_mid[col][32 + quad*8]);   // ks=48 hits the 1.0 bias col
      #pragma unroll
      for (int rt = 0; rt < 3; rt++) {
        const unsigned short* wr = W2e + (rt*16 + l16)*64;
        f32x4 acc = agg[rt];
        acc = MFMA16(ldg8(wr + quad*8),      c0, acc);
        acc = MFMA16(ldg8(wr + 32 + quad*8), c1, acc);
        agg[rt] = acc;
      }
    }

    // ---- GRU ----
    #pragma unroll
    for (int rt = 0; rt < 3; rt++) {
      us4 pk;
      #pragma unroll
      for (int r = 0; r < 4; r++) pk[r] = f2b(agg[rt][r]);
      *(us4*)&s_mid[col][rt*16 + quad*4] = pk;
    }
    bf16x8 ga0 = ldg8(&s_mid[col][quad*8]);
    bf16x8 ga1 = ldg8(&s_mid[col][32 + quad*8]);
    bf16x8 gh0 = ldg8(&hxP[col+1][quad*8]);
    bf16x8 gh1 = ldg8(&hxP[col+1][32 + quad*8]);
    f32x4 rz[6], xn[3], hn[3];
    #pragma unroll
    for (int rt = 0; rt < 6; rt++) {
      const unsigned short* wi = P.Wihb + (rt*16 + l16)*64;
      const unsigned short* wh = P.Whhb + (rt*16 + l16)*64;
      f32x4 acc = {0,0,0,0};
      acc = MFMA16(ldg8(wi + quad*8),      ga0, acc);
      acc = MFMA16(ldg8(wi + 32 + quad*8), ga1, acc);
      acc = MFMA16(ldg8(wh + quad*8),      gh0, acc);
      acc = MFMA16(ldg8(wh + 32 + quad*8), gh1, acc);
      rz[rt] = acc;
    }
    #pragma unroll
    for (int rt = 0; rt < 3; rt++) {
      const unsigned short* wi = P.Wihb + ((96 + rt*16) + l16)*64;
      const unsigned short* wh = P.Whhb + ((96 + rt*16) + l16)*64;
      f32x4 a1 = {0,0,0,0}, a2 = {0,0,0,0};
      a1 = MFMA16(ldg8(wi + quad*8),      ga0, a1);
      a1 = MFMA16(ldg8(wi + 32 + quad*8), ga1, a1);
      a2 = MFMA16(ldg8(wh + quad*8),      gh0, a2);
      a2 = MFMA16(ldg8(wh + 32 + quad*8), gh1, a2);
      xn[rt] = a1; hn[rt] = a2;
    }
    #pragma unroll
    for (int rt = 0; rt < 3; rt++) {
      us4 pk;
      #pragma unroll
      for (int r = 0; r < 4; r++) {
        float rg = 1.f / (1.f + __expf(-rz[rt][r]));
        float zg = 1.f / (1.f + __expf(-rz[3+rt][r]));
        float na = xn[rt][r] + rg * hn[rt][r];
        float e2 = __expf(2.f * na);
        float nn = 1.f - 2.f / (e2 + 1.f);   // tanh
        float hnew = (1.f - zg) * nn + zg * hcur[rt][r];
        if (!gtv) hnew = 0.f;                // true zeros at sequence boundary
        hcur[rt][r] = hnew;
        pk[r] = f2b(hnew);
        if (j == FUSE-1 && eff && gtv) {
          int h = rt*16 + quad*4 + r;
          P.hx_dst[((size_t)b*HD + h)*T_DIM + gt] = hnew;
        }
      }
      *(us4*)&hxN[col+1][rt*16 + quad*4] = pk;
    }

    // ---- decoder + xs update ----
    bf16x8 d0 = ldg8(&hxN[col+1][quad*8]);        // same-wave, in-order
    bf16x8 d1 = ldg8(&hxN[col+1][32 + quad*8]);   // ks=48 -> 1.0 bias col
    f32x4 dec = {0,0,0,0};
    dec = MFMA16(ldg8(P.Wdecb + l16*64 + quad*8),      d0, dec);
    dec = MFMA16(ldg8(P.Wdecb + l16*64 + 32 + quad*8), d1, dec);
    if (quad < 2) {
      f32x4 msum = *(const f32x4*)&s_msum[col][quad*4];
      f32x4 xo;
      #pragma unroll
      for (int r = 0; r < 4; r++) {
        int x = quad*4 + r;
        float xnew = xsP[col+1][x] + GAMMA * (dec[r] + msum[r]);
        if (!gtv) xnew = 0.f;
        xo[r] = xnew;
        if (eff && gtv) {
          out_k[((size_t)b*XD + x)*T_DIM + gt] = xnew;
          if (k == NITER-1) P.out[((size_t)b*XD + x)*T_DIM + gt] = xnew;
        }
      }
      *(f32x4*)&xsN[col+1][quad*4] = xo;
    }

    __syncthreads();   // the ONE barrier: publish hxN/xsN for neighbor waves
  }
}

// ---------------- host launch ----------------
extern "C" void kernel_launch(void* const* d_in, const int* in_sizes, int n_in,
                              void* d_out, int out_size, void* d_ws, size_t ws_size,
                              hipStream_t stream) {
  (void)in_sizes; (void)n_in; (void)out_size; (void)ws_size;
  const float* ys  = (const float*)d_in[0];
  const float* hx0 = (const float*)d_in[1];
  const float* F   = (const float*)d_in[2];
  const float* Hm  = (const float*)d_in[3];
  const float* Q   = (const float*)d_in[4];
  const float* R   = (const float*)d_in[5];

  float* out = (float*)d_out;
  float* ws  = (float*)d_ws;

  const size_t BXT = (size_t)BB * XD * T_DIM;   // 128000
  const size_t BHT = (size_t)BB * HD * T_DIM;   // 768000

  float* mats   = ws;                      // 512
  float* mconst = ws + 512;                // 128000
  float* xs0    = mconst + BXT;            // 128000
  float* hxA    = xs0 + BXT;               // 768000
  float* hxB    = hxA + BHT;               // 768000
  unsigned short* hy_b  = (unsigned short*)(hxB + BHT);   // 768000
  unsigned short* W1b   = hy_b + BHT;                     // 18432
  unsigned short* W2b   = W1b + 3*48*128;                 // 9216
  unsigned short* Wihb  = W2b + 3*48*64;                  // 9216
  unsigned short* Whhb  = Wihb + 144*64;                  // 9216
  unsigned short* Wdecb = Whhb + 144*64;                  // 1024

  precompute_mats_kernel<<<1, 64, 0, stream>>>(F, Hm, Q, R, mats);
  precompute_bt_kernel<<<(BB*T_DIM + 255)/256, 256, 0, stream>>>(
      ys, (const float*)d_in[6], (const float*)d_in[7], Hm, mats, hy_b, mconst, xs0);

  WP wp;
  wp.W1[0] = (const float*)d_in[8];  wp.b1[0] = (const float*)d_in[9];
  wp.W2[0] = (const float*)d_in[10]; wp.b2[0] = (const float*)d_in[11];
  wp.W1[1] = (const float*)d_in[12]; wp.b1[1] = (const float*)d_in[13];
  wp.W2[1] = (const float*)d_in[14]; wp.b2[1] = (const float*)d_in[15];
  wp.W1[2] = (const float*)d_in[16]; wp.b1[2] = (const float*)d_in[17];
  wp.W2[2] = (const float*)d_in[18]; wp.b2[2] = (const float*)d_in[19];
  wp.Wih = (const float*)d_in[20]; wp.bih = (const float*)d_in[21];
  wp.Whh = (const float*)d_in[22]; wp.bhh = (const float*)d_in[23];
  wp.Wdec = (const float*)d_in[24]; wp.bdec = (const float*)d_in[25];
  wp.W1b = W1b; wp.W2b = W2b; wp.Wihb = Wihb; wp.Whhb = Whhb; wp.Wdecb = Wdecb;
  convert_weights_kernel<<<16, 256, 0, stream>>>(wp);

  FP P;
  P.mats = mats; P.mconst = mconst; P.hy_b = hy_b;
  P.W1b = W1b; P.W2b = W2b; P.Wihb = Wihb; P.Whhb = Whhb; P.Wdecb = Wdecb;
  P.out = out;

  for (int L = 0; L < NLNCH; L++) {
    int k0 = L * FUSE;
    P.k0 = k0;
    P.xs_src = (L == 0) ? xs0 : out + BXT + (size_t)(k0 - 1) * BXT;
    P.hx_src = (L == 0) ? hx0 : ((L & 1) ? hxA : hxB);
    P.hx_dst = (L & 1) ? hxB : hxA;
    fused_kernel<<<dim3(BB * NTI), dim3(512), 0, stream>>>(P);
  }
}